// Round 1
// baseline (1494.146 us; speedup 1.0000x reference)
//
#include <hip/hip_runtime.h>

typedef __attribute__((ext_vector_type(8))) short short8;
typedef __attribute__((ext_vector_type(4))) float f32x4;

#define DIM 1024
#define NH 16
#define HD 64
#define LAT 128
#define QR 256
#define BB 4
#define SS 2048
#define BS (BB * SS) /* 8192 */

__device__ __forceinline__ unsigned short f2b(float f) {
  unsigned int u = __builtin_bit_cast(unsigned int, f);
  u += 0x7FFFu + ((u >> 16) & 1u); // RNE
  return (unsigned short)(u >> 16);
}
__device__ __forceinline__ float b2f(unsigned short h) {
  unsigned int u = ((unsigned int)h) << 16;
  return __builtin_bit_cast(float, u);
}

__global__ __launch_bounds__(256) void cvt_x(const float* __restrict__ in,
                                             unsigned short* __restrict__ out, int n4) {
  int i = blockIdx.x * 256 + threadIdx.x;
  if (i >= n4) return;
  f32x4 v = ((const f32x4*)in)[i];
  ushort4 o;
  o.x = f2b(v[0]); o.y = f2b(v[1]); o.z = f2b(v[2]); o.w = f2b(v[3]);
  ((ushort4*)out)[i] = o;
}

__global__ __launch_bounds__(256) void transpose_w(const float* __restrict__ in,
                                                   unsigned short* __restrict__ out,
                                                   int K, int N) {
  int i = blockIdx.x * 256 + threadIdx.x;
  if (i >= K * N) return;
  int n = i / K, k = i - n * K;
  out[i] = f2b(in[(size_t)k * N + n]);
}

// C[M,N] = A[M,K](bf16) @ W (as WT[N,K] bf16) + bias; 64x64/wave, 128x128/block.
__global__ __launch_bounds__(256) void gemm_bf16(const unsigned short* __restrict__ A,
                                                 const unsigned short* __restrict__ WT,
                                                 const float* __restrict__ bias,
                                                 float* __restrict__ outF,
                                                 unsigned short* __restrict__ outB,
                                                 int N, int K, int ldout) {
  const int tid = threadIdx.x;
  const int wave = tid >> 6, lane = tid & 63;
  const int ln = lane & 15, quad = lane >> 4;
  const int m0 = blockIdx.x * 128 + (wave >> 1) * 64;
  const int n0 = blockIdx.y * 128 + (wave & 1) * 64;

  f32x4 acc[4][4];
#pragma unroll
  for (int i = 0; i < 4; i++)
#pragma unroll
    for (int j = 0; j < 4; j++) acc[i][j] = (f32x4){0.f, 0.f, 0.f, 0.f};

  const unsigned short* Ap = A + (size_t)(m0 + ln) * K + quad * 8;
  const unsigned short* Wp = WT + (size_t)(n0 + ln) * K + quad * 8;

  for (int k0 = 0; k0 < K; k0 += 32) {
    short8 a[4], b[4];
#pragma unroll
    for (int i = 0; i < 4; i++) a[i] = *(const short8*)(Ap + (size_t)i * 16 * K + k0);
#pragma unroll
    for (int i = 0; i < 4; i++) b[i] = *(const short8*)(Wp + (size_t)i * 16 * K + k0);
#pragma unroll
    for (int mi = 0; mi < 4; mi++)
#pragma unroll
      for (int ni = 0; ni < 4; ni++)
        acc[mi][ni] =
            __builtin_amdgcn_mfma_f32_16x16x32_bf16(a[mi], b[ni], acc[mi][ni], 0, 0, 0);
  }

#pragma unroll
  for (int mi = 0; mi < 4; mi++) {
    const int row = m0 + mi * 16 + quad * 4;
#pragma unroll
    for (int ni = 0; ni < 4; ni++) {
      const int col = n0 + ni * 16 + ln;
      const float bv = bias[col];
#pragma unroll
      for (int r = 0; r < 4; r++) {
        float v = acc[mi][ni][r] + bv;
        size_t o = (size_t)(row + r) * ldout + col;
        if (outF) outF[o] = v;
        if (outB) outB[o] = f2b(v);
      }
    }
  }
}

__global__ __launch_bounds__(256) void attn_fp32(const unsigned short* __restrict__ Qb,
                                                 const unsigned short* __restrict__ KVb,
                                                 unsigned short* __restrict__ ctxB) {
  __shared__ float Qs[64 * 68];
  __shared__ float KPs[64 * 68]; // K tile, reused as P tile
  __shared__ float Vs[64 * 68];
  const int tid = threadIdx.x;
  const int qt = blockIdx.x, h = blockIdx.y, b = blockIdx.z;
  const int s0 = qt * 64;
  const int rt = tid >> 4, ct = tid & 15;
  const int r0 = rt * 4, c0 = ct * 4;

  for (int idx = tid; idx < 64 * 16; idx += 256) {
    int r = idx >> 4, c4 = (idx & 15) * 4;
    ushort4 v = *(const ushort4*)(Qb + (size_t)(b * SS + s0 + r) * DIM + h * HD + c4);
    f32x4 t = {b2f(v.x), b2f(v.y), b2f(v.z), b2f(v.w)};
    *(f32x4*)&Qs[r * 68 + c4] = t;
  }

  float m_run[4], l_run[4], ctx[4][4];
#pragma unroll
  for (int i = 0; i < 4; i++) {
    m_run[i] = -1e30f;
    l_run[i] = 0.f;
#pragma unroll
    for (int j = 0; j < 4; j++) ctx[i][j] = 0.f;
  }

  for (int kt = 0; kt <= qt; ++kt) {
    __syncthreads();
    for (int idx = tid; idx < 64 * 16; idx += 256) {
      int r = idx >> 4, c4 = (idx & 15) * 4;
      size_t rowb = (size_t)(b * SS + kt * 64 + r) * (2 * DIM);
      ushort4 kv = *(const ushort4*)(KVb + rowb + h * HD + c4);
      ushort4 vv = *(const ushort4*)(KVb + rowb + DIM + h * HD + c4);
      f32x4 tk = {b2f(kv.x), b2f(kv.y), b2f(kv.z), b2f(kv.w)};
      f32x4 tv = {b2f(vv.x), b2f(vv.y), b2f(vv.z), b2f(vv.w)};
      *(f32x4*)&KPs[r * 68 + c4] = tk;
      *(f32x4*)&Vs[r * 68 + c4] = tv;
    }
    __syncthreads();

    float s[4][4];
#pragma unroll
    for (int i = 0; i < 4; i++)
#pragma unroll
      for (int j = 0; j < 4; j++) s[i][j] = 0.f;

#pragma unroll
    for (int dc = 0; dc < 16; ++dc) {
      const int d0 = ((dc + ct) & 15) * 4;
      f32x4 qv[4], kv[4];
#pragma unroll
      for (int i = 0; i < 4; i++) qv[i] = *(const f32x4*)&Qs[(r0 + i) * 68 + d0];
#pragma unroll
      for (int j = 0; j < 4; j++) kv[j] = *(const f32x4*)&KPs[(c0 + j) * 68 + d0];
#pragma unroll
      for (int i = 0; i < 4; i++)
#pragma unroll
        for (int j = 0; j < 4; j++)
          s[i][j] += qv[i][0] * kv[j][0] + qv[i][1] * kv[j][1] + qv[i][2] * kv[j][2] +
                     qv[i][3] * kv[j][3];
    }

    const bool diag = (kt == qt);
    float p[4][4];
#pragma unroll
    for (int i = 0; i < 4; i++) {
#pragma unroll
      for (int j = 0; j < 4; j++) {
        float sv = s[i][j] * 0.125f;
        if (diag && (c0 + j) > (r0 + i)) sv = -1e30f;
        s[i][j] = sv;
      }
      float mx = fmaxf(fmaxf(s[i][0], s[i][1]), fmaxf(s[i][2], s[i][3]));
#pragma unroll
      for (int off = 1; off < 16; off <<= 1) mx = fmaxf(mx, __shfl_xor(mx, off, 64));
      const float mnew = fmaxf(m_run[i], mx);
      const float alpha = __expf(m_run[i] - mnew);
      float rs = 0.f;
#pragma unroll
      for (int j = 0; j < 4; j++) {
        p[i][j] = __expf(s[i][j] - mnew);
        rs += p[i][j];
      }
#pragma unroll
      for (int off = 1; off < 16; off <<= 1) rs += __shfl_xor(rs, off, 64);
      l_run[i] = l_run[i] * alpha + rs;
      m_run[i] = mnew;
#pragma unroll
      for (int j = 0; j < 4; j++) ctx[i][j] *= alpha;
    }

    __syncthreads();
#pragma unroll
    for (int i = 0; i < 4; i++) {
      f32x4 pv = {p[i][0], p[i][1], p[i][2], p[i][3]};
      *(f32x4*)&KPs[(r0 + i) * 68 + c0] = pv;
    }
    __syncthreads();

#pragma unroll
    for (int t0 = 0; t0 < 16; ++t0) {
      f32x4 pr[4];
#pragma unroll
      for (int i = 0; i < 4; i++) pr[i] = *(const f32x4*)&KPs[(r0 + i) * 68 + t0 * 4];
#pragma unroll
      for (int k = 0; k < 4; k++) {
        f32x4 vv = *(const f32x4*)&Vs[(t0 * 4 + k) * 68 + c0];
#pragma unroll
        for (int i = 0; i < 4; i++) {
          const float pk = pr[i][k];
#pragma unroll
          for (int j = 0; j < 4; j++) ctx[i][j] += pk * vv[j];
        }
      }
    }
  }

#pragma unroll
  for (int i = 0; i < 4; i++) {
    const float inv = 1.f / l_run[i];
    ushort4 o;
    o.x = f2b(ctx[i][0] * inv);
    o.y = f2b(ctx[i][1] * inv);
    o.z = f2b(ctx[i][2] * inv);
    o.w = f2b(ctx[i][3] * inv);
    *(ushort4*)(ctxB + (size_t)(b * SS + s0 + r0 + i) * DIM + h * HD + c0) = o;
  }
}

extern "C" void kernel_launch(void* const* d_in, const int* in_sizes, int n_in,
                              void* d_out, int out_size, void* d_ws, size_t ws_size,
                              hipStream_t stream) {
  const float* x     = (const float*)d_in[0];
  const float* w_kvc = (const float*)d_in[2];
  const float* b_kvc = (const float*)d_in[3];
  const float* w_kvu = (const float*)d_in[4];
  const float* b_kvu = (const float*)d_in[5];
  const float* w_qc  = (const float*)d_in[6];
  const float* b_qc  = (const float*)d_in[7];
  const float* w_qu  = (const float*)d_in[8];
  const float* b_qu  = (const float*)d_in[9];
  const float* w_o   = (const float*)d_in[10];
  const float* b_o   = (const float*)d_in[11];
  float* out = (float*)d_out;

  unsigned short* xb    = (unsigned short*)d_ws;
  unsigned short* wkvcT = xb + (size_t)BS * DIM;
  unsigned short* wkvuT = wkvcT + (size_t)DIM * LAT;
  unsigned short* wqcT  = wkvuT + (size_t)LAT * 2 * DIM;
  unsigned short* wquT  = wqcT + (size_t)DIM * QR;
  unsigned short* woT   = wquT + (size_t)QR * DIM;
  unsigned short* kvlat = woT + (size_t)DIM * DIM;
  unsigned short* qlat  = kvlat + (size_t)BS * LAT;
  unsigned short* kvup  = qlat + (size_t)BS * QR;
  unsigned short* Qbuf  = kvup + (size_t)BS * 2 * DIM;
  unsigned short* ctx   = Qbuf + (size_t)BS * DIM;

  cvt_x<<<(BS * DIM / 4 + 255) / 256, 256, 0, stream>>>(x, xb, BS * DIM / 4);
  transpose_w<<<(DIM * LAT + 255) / 256, 256, 0, stream>>>(w_kvc, wkvcT, DIM, LAT);
  transpose_w<<<(LAT * 2 * DIM + 255) / 256, 256, 0, stream>>>(w_kvu, wkvuT, LAT, 2 * DIM);
  transpose_w<<<(DIM * QR + 255) / 256, 256, 0, stream>>>(w_qc, wqcT, DIM, QR);
  transpose_w<<<(QR * DIM + 255) / 256, 256, 0, stream>>>(w_qu, wquT, QR, DIM);
  transpose_w<<<(DIM * DIM + 255) / 256, 256, 0, stream>>>(w_o, woT, DIM, DIM);

  gemm_bf16<<<dim3(BS / 128, LAT / 128), 256, 0, stream>>>(xb, wkvcT, b_kvc, nullptr,
                                                           kvlat, LAT, DIM, LAT);
  gemm_bf16<<<dim3(BS / 128, QR / 128), 256, 0, stream>>>(xb, wqcT, b_qc, nullptr, qlat,
                                                          QR, DIM, QR);
  gemm_bf16<<<dim3(BS / 128, 2 * DIM / 128), 256, 0, stream>>>(
      kvlat, wkvuT, b_kvu, nullptr, kvup, 2 * DIM, LAT, 2 * DIM);
  gemm_bf16<<<dim3(BS / 128, DIM / 128), 256, 0, stream>>>(qlat, wquT, b_qu, nullptr,
                                                           Qbuf, DIM, QR, DIM);
  attn_fp32<<<dim3(SS / 64, NH, BB), 256, 0, stream>>>(Qbuf, kvup, ctx);
  gemm_bf16<<<dim3(BS / 128, DIM / 128), 256, 0, stream>>>(ctx, woT, b_o, out, nullptr,
                                                           DIM, DIM, DIM);
}

// Round 2
// 547.516 us; speedup vs baseline: 2.7290x; 2.7290x over previous
//
#include <hip/hip_runtime.h>

typedef __attribute__((ext_vector_type(8))) short short8;
typedef __attribute__((ext_vector_type(4))) float f32x4;

#define DIM 1024
#define NH 16
#define HD 64
#define LAT 128
#define QR 256
#define BB 4
#define SS 2048
#define BS (BB * SS) /* 8192 */

__device__ __forceinline__ unsigned short f2b(float f) {
  unsigned int u = __builtin_bit_cast(unsigned int, f);
  u += 0x7FFFu + ((u >> 16) & 1u); // RNE
  return (unsigned short)(u >> 16);
}
__device__ __forceinline__ float b2f(unsigned short h) {
  unsigned int u = ((unsigned int)h) << 16;
  return __builtin_bit_cast(float, u);
}

__global__ __launch_bounds__(256) void cvt_x(const float* __restrict__ in,
                                             unsigned short* __restrict__ out, int n4) {
  int i = blockIdx.x * 256 + threadIdx.x;
  if (i >= n4) return;
  f32x4 v = ((const f32x4*)in)[i];
  ushort4 o;
  o.x = f2b(v[0]); o.y = f2b(v[1]); o.z = f2b(v[2]); o.w = f2b(v[3]);
  ((ushort4*)out)[i] = o;
}

__global__ __launch_bounds__(256) void transpose_w(const float* __restrict__ in,
                                                   unsigned short* __restrict__ out,
                                                   int K, int N) {
  int i = blockIdx.x * 256 + threadIdx.x;
  if (i >= K * N) return;
  int n = i / K, k = i - n * K;
  out[i] = f2b(in[(size_t)k * N + n]);
}

// V (cols DIM..2*DIM of kvup, [b*SS+s][2*DIM]) -> VT[b][d][s]  (bf16)
__global__ __launch_bounds__(256) void transpose_v(const unsigned short* __restrict__ KVb,
                                                   unsigned short* __restrict__ VTb) {
  __shared__ unsigned short T[64 * 72];
  const int tid = threadIdx.x;
  const int st = blockIdx.x, dt = blockIdx.y, b = blockIdx.z;
  const int s0 = st * 64, d0 = dt * 64;
#pragma unroll
  for (int t = 0; t < 2; ++t) {
    int idx = tid + t * 256;
    int r = idx >> 3, c = idx & 7; // r = seq-in-tile, c = d-chunk of 8
    short8 v = *(const short8*)(KVb + (size_t)(b * SS + s0 + r) * (2 * DIM) + DIM + d0 + c * 8);
    *(short8*)(T + r * 72 + c * 8) = v;
  }
  __syncthreads();
#pragma unroll
  for (int t = 0; t < 2; ++t) {
    int idx = tid + t * 256;
    int dr = idx >> 3, cg = idx & 7; // dr = d-in-tile, cg = seq-chunk of 8
    short8 o;
#pragma unroll
    for (int i = 0; i < 8; i++) o[i] = T[(cg * 8 + i) * 72 + dr];
    *(short8*)(VTb + (size_t)(b * DIM + d0 + dr) * SS + s0 + cg * 8) = o;
  }
}

// C[M,N] = A[M,K](bf16) @ W (as WT[N,K] bf16) + bias; 64x64/wave, 128x128/block.
__global__ __launch_bounds__(256) void gemm_bf16(const unsigned short* __restrict__ A,
                                                 const unsigned short* __restrict__ WT,
                                                 const float* __restrict__ bias,
                                                 float* __restrict__ outF,
                                                 unsigned short* __restrict__ outB,
                                                 int N, int K, int ldout) {
  const int tid = threadIdx.x;
  const int wave = tid >> 6, lane = tid & 63;
  const int ln = lane & 15, quad = lane >> 4;
  const int m0 = blockIdx.x * 128 + (wave >> 1) * 64;
  const int n0 = blockIdx.y * 128 + (wave & 1) * 64;

  f32x4 acc[4][4];
#pragma unroll
  for (int i = 0; i < 4; i++)
#pragma unroll
    for (int j = 0; j < 4; j++) acc[i][j] = (f32x4){0.f, 0.f, 0.f, 0.f};

  const unsigned short* Ap = A + (size_t)(m0 + ln) * K + quad * 8;
  const unsigned short* Wp = WT + (size_t)(n0 + ln) * K + quad * 8;

  for (int k0 = 0; k0 < K; k0 += 32) {
    short8 a[4], b[4];
#pragma unroll
    for (int i = 0; i < 4; i++) a[i] = *(const short8*)(Ap + (size_t)i * 16 * K + k0);
#pragma unroll
    for (int i = 0; i < 4; i++) b[i] = *(const short8*)(Wp + (size_t)i * 16 * K + k0);
#pragma unroll
    for (int mi = 0; mi < 4; mi++)
#pragma unroll
      for (int ni = 0; ni < 4; ni++)
        acc[mi][ni] =
            __builtin_amdgcn_mfma_f32_16x16x32_bf16(a[mi], b[ni], acc[mi][ni], 0, 0, 0);
  }

#pragma unroll
  for (int mi = 0; mi < 4; mi++) {
    const int row = m0 + mi * 16 + quad * 4;
#pragma unroll
    for (int ni = 0; ni < 4; ni++) {
      const int col = n0 + ni * 16 + ln;
      const float bv = bias[col];
#pragma unroll
      for (int r = 0; r < 4; r++) {
        float v = acc[mi][ni][r] + bv;
        size_t o = (size_t)(row + r) * ldout + col;
        if (outF) outF[o] = v;
        if (outB) outB[o] = f2b(v);
      }
    }
  }
}

// MFMA flash attention, causal. Block = 64 Q rows x (head, batch); 4 waves,
// wave w owns Q rows [w*16, w*16+16). K-tiles of 64 keys.
// Layouts (verified m89/m91): A-frag a[j]=A[m=ln][k=quad*8+j];
// B-frag b[j]=Bop[n=ln][k=quad*8+j] (Bop stored [n][k]); C/D col=ln,row=quad*4+r.
// LDS rows padded to 72 shorts: b128 frag reads land on bank group
// 4*((ln+quad)%8) -> balanced 8-way (the inherent b128 serialization).
__global__ __launch_bounds__(256) void attn_mfma(const unsigned short* __restrict__ Qb,
                                                 const unsigned short* __restrict__ KVb,
                                                 const unsigned short* __restrict__ VTb,
                                                 unsigned short* __restrict__ ctxB) {
  __shared__ unsigned short Ks[64 * 72];  // K tile [key][d]; reused for ctx at end
  __shared__ unsigned short Vts[64 * 72]; // V^T tile [d][key]
  __shared__ unsigned short Ps[4 * 16 * 72]; // per-wave P [q][key]
  const int tid = threadIdx.x;
  const int wave = tid >> 6, lane = tid & 63;
  const int ln = lane & 15, quad = lane >> 4;
  const int qt = blockIdx.x, h = blockIdx.y, b = blockIdx.z;
  const int s0 = qt * 64;

  short8 qfrag[2];
  {
    const unsigned short* qp =
        Qb + (size_t)(b * SS + s0 + wave * 16 + ln) * DIM + h * HD + quad * 8;
    qfrag[0] = *(const short8*)qp;
    qfrag[1] = *(const short8*)(qp + 32);
  }

  f32x4 octx[4]; // PV acc: tile dt -> col d=dt*16+ln, row q=quad*4+r
  float m_run[4], l_run[4];
#pragma unroll
  for (int i = 0; i < 4; i++) octx[i] = (f32x4){0.f, 0.f, 0.f, 0.f};
#pragma unroll
  for (int r = 0; r < 4; r++) { m_run[r] = -1e30f; l_run[r] = 0.f; }

  unsigned short* Pw = Ps + wave * (16 * 72);

  for (int kt = 0; kt <= qt; ++kt) {
    __syncthreads(); // prior-iter Vts/Ks readers done
#pragma unroll
    for (int t = 0; t < 2; ++t) { // stage K tile [key][d]
      int idx = tid + t * 256;
      int row = idx >> 3, c = idx & 7;
      short8 v = *(const short8*)(KVb + (size_t)(b * SS + kt * 64 + row) * (2 * DIM) +
                                  h * HD + c * 8);
      *(short8*)(Ks + row * 72 + c * 8) = v;
    }
#pragma unroll
    for (int t = 0; t < 2; ++t) { // stage V^T tile [d][key]
      int idx = tid + t * 256;
      int d = idx >> 3, c = idx & 7;
      short8 v =
          *(const short8*)(VTb + (size_t)(b * DIM + h * HD + d) * SS + kt * 64 + c * 8);
      *(short8*)(Vts + d * 72 + c * 8) = v;
    }
    __syncthreads();

    const bool diag = (kt == qt);
    f32x4 sacc[4];
#pragma unroll
    for (int nt = 0; nt < 4; nt++) sacc[nt] = (f32x4){0.f, 0.f, 0.f, 0.f};
#pragma unroll
    for (int kc = 0; kc < 2; kc++) {
#pragma unroll
      for (int nt = 0; nt < 4; nt++) {
        if (diag && nt > wave) continue; // fully-masked cols for this wave
        short8 bfrag = *(const short8*)(Ks + (nt * 16 + ln) * 72 + kc * 32 + quad * 8);
        sacc[nt] =
            __builtin_amdgcn_mfma_f32_16x16x32_bf16(qfrag[kc], bfrag, sacc[nt], 0, 0, 0);
      }
    }

    float p[4][4]; // [r][nt]
#pragma unroll
    for (int r = 0; r < 4; r++) {
      const int qrow = wave * 16 + quad * 4 + r; // within block tile
      float sv[4];
#pragma unroll
      for (int nt = 0; nt < 4; nt++) {
        float x = sacc[nt][r] * 0.125f; // 1/sqrt(64)
        if (diag && (nt * 16 + ln) > qrow) x = -1e30f;
        sv[nt] = x;
      }
      float mx = fmaxf(fmaxf(sv[0], sv[1]), fmaxf(sv[2], sv[3]));
#pragma unroll
      for (int off = 1; off < 16; off <<= 1) mx = fmaxf(mx, __shfl_xor(mx, off, 64));
      const float mnew = fmaxf(m_run[r], mx);
      const float alpha = __expf(m_run[r] - mnew);
      float rs = 0.f;
#pragma unroll
      for (int nt = 0; nt < 4; nt++) {
        p[r][nt] = __expf(sv[nt] - mnew);
        rs += p[r][nt];
      }
#pragma unroll
      for (int off = 1; off < 16; off <<= 1) rs += __shfl_xor(rs, off, 64);
      m_run[r] = mnew;
      l_run[r] = l_run[r] * alpha + rs;
#pragma unroll
      for (int dt = 0; dt < 4; dt++) octx[dt][r] *= alpha;
    }

    // P (C-layout regs) -> per-wave LDS [q][key] bf16; same-wave write->read,
    // no barrier needed (lgkmcnt ordering within wave).
#pragma unroll
    for (int r = 0; r < 4; r++)
#pragma unroll
      for (int nt = 0; nt < 4; nt++)
        Pw[(quad * 4 + r) * 72 + nt * 16 + ln] = f2b(p[r][nt]);

#pragma unroll
    for (int kc = 0; kc < 2; kc++) {
      if (diag && kc == 1 && wave < 2) continue; // P cols 32..63 all zero
      short8 pfrag = *(const short8*)(Pw + ln * 72 + kc * 32 + quad * 8);
#pragma unroll
      for (int dt = 0; dt < 4; dt++) {
        short8 vfrag = *(const short8*)(Vts + (dt * 16 + ln) * 72 + kc * 32 + quad * 8);
        octx[dt] =
            __builtin_amdgcn_mfma_f32_16x16x32_bf16(pfrag, vfrag, octx[dt], 0, 0, 0);
      }
    }
  }

  // Epilogue: normalize, round-trip through Ks for coalesced 16B stores.
  __syncthreads();
#pragma unroll
  for (int r = 0; r < 4; r++) {
    const float inv = 1.f / l_run[r];
#pragma unroll
    for (int dt = 0; dt < 4; dt++)
      Ks[(wave * 16 + quad * 4 + r) * 72 + dt * 16 + ln] = f2b(octx[dt][r] * inv);
  }
  __syncthreads();
#pragma unroll
  for (int t = 0; t < 2; ++t) {
    int idx = tid + t * 256;
    int row = idx >> 3, c = idx & 7;
    short8 v = *(const short8*)(Ks + row * 72 + c * 8);
    *(short8*)(ctxB + (size_t)(b * SS + s0 + row) * DIM + h * HD + c * 8) = v;
  }
}

extern "C" void kernel_launch(void* const* d_in, const int* in_sizes, int n_in,
                              void* d_out, int out_size, void* d_ws, size_t ws_size,
                              hipStream_t stream) {
  const float* x     = (const float*)d_in[0];
  const float* w_kvc = (const float*)d_in[2];
  const float* b_kvc = (const float*)d_in[3];
  const float* w_kvu = (const float*)d_in[4];
  const float* b_kvu = (const float*)d_in[5];
  const float* w_qc  = (const float*)d_in[6];
  const float* b_qc  = (const float*)d_in[7];
  const float* w_qu  = (const float*)d_in[8];
  const float* b_qu  = (const float*)d_in[9];
  const float* w_o   = (const float*)d_in[10];
  const float* b_o   = (const float*)d_in[11];
  float* out = (float*)d_out;

  unsigned short* xb    = (unsigned short*)d_ws;        // [BS][DIM]; reused as VT later
  unsigned short* wkvcT = xb + (size_t)BS * DIM;
  unsigned short* wkvuT = wkvcT + (size_t)DIM * LAT;
  unsigned short* wqcT  = wkvuT + (size_t)LAT * 2 * DIM;
  unsigned short* wquT  = wqcT + (size_t)DIM * QR;
  unsigned short* woT   = wquT + (size_t)QR * DIM;
  unsigned short* kvlat = woT + (size_t)DIM * DIM;
  unsigned short* qlat  = kvlat + (size_t)BS * LAT;
  unsigned short* kvup  = qlat + (size_t)BS * QR;
  unsigned short* Qbuf  = kvup + (size_t)BS * 2 * DIM;
  unsigned short* ctx   = Qbuf + (size_t)BS * DIM;

  cvt_x<<<(BS * DIM / 4 + 255) / 256, 256, 0, stream>>>(x, xb, BS * DIM / 4);
  transpose_w<<<(DIM * LAT + 255) / 256, 256, 0, stream>>>(w_kvc, wkvcT, DIM, LAT);
  transpose_w<<<(LAT * 2 * DIM + 255) / 256, 256, 0, stream>>>(w_kvu, wkvuT, LAT, 2 * DIM);
  transpose_w<<<(DIM * QR + 255) / 256, 256, 0, stream>>>(w_qc, wqcT, DIM, QR);
  transpose_w<<<(QR * DIM + 255) / 256, 256, 0, stream>>>(w_qu, wquT, QR, DIM);
  transpose_w<<<(DIM * DIM + 255) / 256, 256, 0, stream>>>(w_o, woT, DIM, DIM);

  gemm_bf16<<<dim3(BS / 128, LAT / 128), 256, 0, stream>>>(xb, wkvcT, b_kvc, nullptr,
                                                           kvlat, LAT, DIM, LAT);
  gemm_bf16<<<dim3(BS / 128, QR / 128), 256, 0, stream>>>(xb, wqcT, b_qc, nullptr, qlat,
                                                          QR, DIM, QR);
  gemm_bf16<<<dim3(BS / 128, 2 * DIM / 128), 256, 0, stream>>>(
      kvlat, wkvuT, b_kvu, nullptr, kvup, 2 * DIM, LAT, 2 * DIM);
  // xb (x in bf16) is dead now -> reuse as VT[b][d][s] (same element count)
  unsigned short* VT = xb;
  transpose_v<<<dim3(SS / 64, DIM / 64, BB), 256, 0, stream>>>(kvup, VT);
  gemm_bf16<<<dim3(BS / 128, DIM / 128), 256, 0, stream>>>(qlat, wquT, b_qu, nullptr,
                                                           Qbuf, DIM, QR, DIM);
  attn_mfma<<<dim3(SS / 64, NH, BB), 256, 0, stream>>>(Qbuf, kvup, VT, ctx);
  gemm_bf16<<<dim3(BS / 128, DIM / 128), 256, 0, stream>>>(ctx, woT, b_o, out, nullptr,
                                                           DIM, DIM, DIM);
}